// Round 7
// baseline (371.080 us; speedup 1.0000x reference)
//
#include <hip/hip_runtime.h>

#define TPB 256

static constexpr int   HWc  = 16384;                 // 128*128
static constexpr float NINV = 1.0f / 1048576.0f;     // 1/(B*H*W)

static constexpr unsigned FI_OFF    = 0u;
static constexpr unsigned WI_OFF    = 15728640u;
static constexpr unsigned VALS_OFF  = 15728960u;
static constexpr unsigned ORDER_OFF = 15729984u;
static constexpr unsigned CGH_OFF   = 15731008u;

typedef _Float16 f16;
typedef f16   f16x8 __attribute__((ext_vector_type(8)));
typedef f16   f16x4 __attribute__((ext_vector_type(4)));
typedef float f32x4 __attribute__((ext_vector_type(4)));

// async global->LDS, 16B per lane; LDS dest = wave base + lane*16 (linear layout)
__device__ __forceinline__ void gl_lds16(const void* g, void* l) {
    __builtin_amdgcn_global_load_lds(
        (const __attribute__((address_space(1))) unsigned int*)g,
        (__attribute__((address_space(3))) unsigned int*)l, 16, 0, 0);
}

__device__ __forceinline__ float wave_sum(float v) {
#pragma unroll
    for (int o = 1; o < 64; o <<= 1) v += __shfl_xor(v, o, 64);
    return v;
}

// fast tanh: 1 - 2/(e^{2x}+1); v_exp_f32 + v_rcp_f32, ~1e-6 rel, exact saturation
__device__ __forceinline__ float tanh_fast(float x) {
    float e = __expf(x + x);
    return 1.0f - __fdividef(2.0f, e + 1.0f);
}

// ---- Pass A: Gram of x (16x16) + col sums via MFMA -> stats1 analytically ----
__global__ __launch_bounds__(TPB) void k_gramx(const float* __restrict__ x,
                                               float* __restrict__ bkt) {
    __shared__ float red[4][272];
    int tid = threadIdx.x, lane = tid & 63, w = tid >> 6;
    int p = lane & 15, g = lane >> 4;
    const f16 one = (f16)1.0f;
    const f16x8 kOnes = {one, one, one, one, one, one, one, one};
    f32x4 accG = {0.f, 0.f, 0.f, 0.f};
    f32x4 accS = {0.f, 0.f, 0.f, 0.f};
    unsigned wgid = blockIdx.x * 4u + (unsigned)w;
    for (unsigned c = wgid; c < 32768u; c += 2048u) {   // 32 px per chunk
        unsigned P0 = c * 32u;
        unsigned b = P0 >> 14, off = P0 & 16383u;
        const float* src = x + ((size_t)b * 16 + p) * HWc + off + g * 8;
        float4 a4 = *(const float4*)src;
        float4 b4 = *(const float4*)(src + 4);
        f16x8 f = { (f16)a4.x, (f16)a4.y, (f16)a4.z, (f16)a4.w,
                    (f16)b4.x, (f16)b4.y, (f16)b4.z, (f16)b4.w };
        accG = __builtin_amdgcn_mfma_f32_16x16x32_f16(f, f, accG, 0, 0, 0);
        accS = __builtin_amdgcn_mfma_f32_16x16x32_f16(kOnes, f, accS, 0, 0, 0);
    }
#pragma unroll
    for (int r = 0; r < 4; ++r) red[w][(4 * g + r) * 16 + p] = accG[r];
    if (g == 0) red[w][256 + p] = accS[0];
    __syncthreads();
    for (int e = tid; e < 272; e += TPB) {
        float v = red[0][e] + red[1][e] + red[2][e] + red[3][e];
        atomicAdd(&bkt[(blockIdx.x & 63u) * 272u + (unsigned)e], v);
    }
}

// ---- stats1 finalize: G_x -> mean/var of conv1 raw -> (scale, shift) ----
__global__ void k_sfin1g(const float* __restrict__ bkt, const float* __restrict__ w1,
                         const float* __restrict__ g1, const float* __restrict__ bb1,
                         float* __restrict__ prm) {
    __shared__ float G[256];
    __shared__ float S[16];
    int tid = threadIdx.x;   // 256
    {
        float v = 0.f;
        for (int s = 0; s < 64; ++s) v += bkt[s * 272 + tid];
        G[tid] = v;
    }
    if (tid < 16) {
        float v = 0.f;
        for (int s = 0; s < 64; ++s) v += bkt[s * 272 + 256 + tid];
        S[tid] = v;
    }
    __syncthreads();
    if (tid < 32) {
        float wv[16];
#pragma unroll
        for (int i = 0; i < 16; ++i) wv[i] = w1[tid * 16 + i];
        float m = 0.f, e2 = 0.f;
#pragma unroll
        for (int i = 0; i < 16; ++i) {
            m += wv[i] * S[i];
            float t = 0.f;
#pragma unroll
            for (int j = 0; j < 16; ++j) t += wv[j] * G[i * 16 + j];
            e2 += wv[i] * t;
        }
        float mean = m * NINV;
        float var = e2 * NINV - mean * mean;
        float sc = g1[tid] * rsqrtf(var + 1e-5f);
        prm[tid * 2] = sc;
        prm[tid * 2 + 1] = bb1[tid] - mean * sc;
    }
}

// ---- Pass B: conv1 scalar + BN1/ReLU -> v1 fp16 -> LDS -> MFMA conv2 raw out
//      + MFMA Gram(v1) for stats2. ----
__global__ __launch_bounds__(TPB) void k_conv2m(const float* __restrict__ x,
                                                const float* __restrict__ w1,
                                                const float* __restrict__ w2,
                                                const float* __restrict__ prm1,
                                                f16* __restrict__ t2r,
                                                float* __restrict__ bkt) {
    __shared__ __align__(16) float w1s[512];
    __shared__ float p1[64];
    __shared__ __align__(16) f16 V[256 * 40];   // [px][32ch] pad->40
    __shared__ float red[4][800];
    int tid = threadIdx.x, lane = tid & 63, w = tid >> 6;
    int p = lane & 15, g = lane >> 4;
    for (int e = tid; e < 512; e += TPB) w1s[e] = w1[e];
    if (tid < 64) p1[tid] = prm1[tid];
    // W2 fragments: lane (p,g) of block cb holds W2[cb*16+p][g*8..+7] fp16
    f16x8 Wf[4];
#pragma unroll
    for (int cb = 0; cb < 4; ++cb) {
        const float* wr = w2 + (cb * 16 + p) * 32 + g * 8;
        float4 a4 = *(const float4*)wr;
        float4 b4 = *(const float4*)(wr + 4);
        Wf[cb] = (f16x8){ (f16)a4.x, (f16)a4.y, (f16)a4.z, (f16)a4.w,
                          (f16)b4.x, (f16)b4.y, (f16)b4.z, (f16)b4.w };
    }
    __syncthreads();
    unsigned pid = blockIdx.x * TPB + tid;
    const float* xp = x + (size_t)(pid >> 14) * 16 * HWc + (pid & 16383u);
    float xv[16];
#pragma unroll
    for (int c = 0; c < 16; ++c) xv[c] = xp[(size_t)c * HWc];
    f16* vp = V + tid * 40;
#pragma unroll
    for (int c8 = 0; c8 < 4; ++c8) {
        f16x8 hv;
#pragma unroll
        for (int j = 0; j < 8; ++j) {
            int co = c8 * 8 + j;
            float a = 0.f;
#pragma unroll
            for (int c4 = 0; c4 < 4; ++c4) {
                float4 ww = *(const float4*)&w1s[co * 16 + c4 * 4];
                a = fmaf(xv[c4 * 4 + 0], ww.x, a); a = fmaf(xv[c4 * 4 + 1], ww.y, a);
                a = fmaf(xv[c4 * 4 + 2], ww.z, a); a = fmaf(xv[c4 * 4 + 3], ww.w, a);
            }
            hv[j] = (f16)fmaxf(0.f, fmaf(a, p1[co * 2], p1[co * 2 + 1]));
        }
        *(f16x8*)(vp + c8 * 8) = hv;
    }
    __syncthreads();
    // conv2: wave w owns px [w*64, w*64+64)
    unsigned Pb = blockIdx.x * TPB + (unsigned)(w * 64);
#pragma unroll
    for (int f = 0; f < 4; ++f) {
        int pxl = w * 64 + f * 16 + p;
        f16x8 bf = *(const f16x8*)&V[pxl * 40 + g * 8];
        unsigned Pg = Pb + (unsigned)(f * 16 + p);
#pragma unroll
        for (int cb = 0; cb < 4; ++cb) {
            f32x4 d = {0.f, 0.f, 0.f, 0.f};
            d = __builtin_amdgcn_mfma_f32_16x16x32_f16(Wf[cb], bf, d, 0, 0, 0);
            f16x4 o4 = { (f16)d[0], (f16)d[1], (f16)d[2], (f16)d[3] };
            *(f16x4*)(t2r + (size_t)Pg * 64 + cb * 16 + 4 * g) = o4;
        }
    }
    // Gram(v1): 32x32 in 3 blocks (0,0),(0,1),(1,1) + col sums
    const f16 one = (f16)1.0f;
    const f16x8 kOnes = {one, one, one, one, one, one, one, one};
    f32x4 accG[3] = {{0.f,0.f,0.f,0.f},{0.f,0.f,0.f,0.f},{0.f,0.f,0.f,0.f}};
    f32x4 accS[2] = {{0.f,0.f,0.f,0.f},{0.f,0.f,0.f,0.f}};
#pragma unroll
    for (int c2 = 0; c2 < 2; ++c2) {
        int px0 = w * 64 + c2 * 32;
        f16x8 fb[2];
#pragma unroll
        for (int cb2 = 0; cb2 < 2; ++cb2)
#pragma unroll
            for (int j = 0; j < 8; ++j)
                fb[cb2][j] = V[(px0 + g * 8 + j) * 40 + cb2 * 16 + p];
        accG[0] = __builtin_amdgcn_mfma_f32_16x16x32_f16(fb[0], fb[0], accG[0], 0, 0, 0);
        accG[1] = __builtin_amdgcn_mfma_f32_16x16x32_f16(fb[0], fb[1], accG[1], 0, 0, 0);
        accG[2] = __builtin_amdgcn_mfma_f32_16x16x32_f16(fb[1], fb[1], accG[2], 0, 0, 0);
        accS[0] = __builtin_amdgcn_mfma_f32_16x16x32_f16(kOnes, fb[0], accS[0], 0, 0, 0);
        accS[1] = __builtin_amdgcn_mfma_f32_16x16x32_f16(kOnes, fb[1], accS[1], 0, 0, 0);
    }
#pragma unroll
    for (int blk = 0; blk < 3; ++blk)
#pragma unroll
        for (int r = 0; r < 4; ++r)
            red[w][blk * 256 + (4 * g + r) * 16 + p] = accG[blk][r];
    if (g == 0) { red[w][768 + p] = accS[0][0]; red[w][784 + p] = accS[1][0]; }
    __syncthreads();
    for (int e = tid; e < 800; e += TPB) {
        float v = red[0][e] + red[1][e] + red[2][e] + red[3][e];
        atomicAdd(&bkt[(blockIdx.x & 63u) * 800u + (unsigned)e], v);
    }
}

// ---- stats2 finalize: Gram(v1) -> mean/var of conv2 raw (fp16-consistent W2) ----
__global__ void k_sfin2g(const float* __restrict__ bkt, const float* __restrict__ w2,
                         const float* __restrict__ g2, const float* __restrict__ bb2,
                         float* __restrict__ prm) {
    __shared__ float G[768];
    __shared__ float S[32];
    int tid = threadIdx.x;   // 256
    for (int e = tid; e < 768; e += 256) {
        float v = 0.f;
        for (int s = 0; s < 64; ++s) v += bkt[s * 800 + e];
        G[e] = v;
    }
    if (tid < 32) {
        float v = 0.f;
        for (int s = 0; s < 64; ++s) v += bkt[s * 800 + 768 + tid];
        S[tid] = v;
    }
    __syncthreads();
    if (tid < 64) {
        float wv[32];
#pragma unroll
        for (int i = 0; i < 32; ++i) wv[i] = (float)(f16)w2[tid * 32 + i];
        float m = 0.f, e2 = 0.f;
#pragma unroll
        for (int i = 0; i < 32; ++i) {
            m += wv[i] * S[i];
            int bi = i >> 4, il = i & 15;
            float t = 0.f;
#pragma unroll
            for (int j = 0; j < 32; ++j) {
                int bj = j >> 4, jl = j & 15;
                float Gij;
                if (bi <= bj) Gij = G[(bi == 0 ? (bj == 0 ? 0 : 1) : 2) * 256 + il * 16 + jl];
                else          Gij = G[(bj == 0 ? 1 : 2) * 256 + jl * 16 + il];
                t += wv[j] * Gij;
            }
            e2 += wv[i] * t;
        }
        float mean = m * NINV;
        float var = e2 * NINV - mean * mean;
        float sc = g2[tid] * rsqrtf(var + 1e-5f);
        prm[tid * 2] = sc;
        prm[tid * 2 + 1] = bb2[tid] - mean * sc;
    }
}

// ------------- generic stats finalize (sum/sumsq buckets, conv3/conv4) -------------
__global__ void k_sfin(const float* __restrict__ bkt, const float* __restrict__ g,
                       const float* __restrict__ bb, float* __restrict__ prm, int C) {
    int co = threadIdx.x;
    float s = 0.f, q = 0.f;
    for (int k = 0; k < 64; ++k) { s += bkt[(k * C + co) * 2]; q += bkt[(k * C + co) * 2 + 1]; }
    float mean = s * NINV;
    float var = q * NINV - mean * mean;
    float sc = g[co] * rsqrtf(var + 1e-5f);
    prm[co * 2] = sc;
    prm[co * 2 + 1] = bb[co] - mean * sc;
}

// ---- weight prep: OIHW fp32 -> fp16 frags, PRE-SCALED by input-BN scale ----
// w'[co][ci][tap] = w * sc[ci]; staging then only applies ReLU(t + sh/sc).
// MUST launch after the corresponding stats finalize.
template <int CI>
__global__ void k_wprep(const float* __restrict__ w, const float* __restrict__ prm,
                        float* __restrict__ wsg) {
    constexpr int KS = CI / 32;
    int t = blockIdx.x * 256 + threadIdx.x;
    if (t >= KS * 18 * 64) return;
    int lane = t & 63, fr = t >> 6;
    int cf = fr & 1, tap = (fr >> 1) % 9, ks = fr / 18;
    int g = lane >> 4, p = lane & 15;
    int co = cf * 16 + p;
    f16x8 hv;
#pragma unroll
    for (int j = 0; j < 8; ++j) {
        int ci = ks * 32 + g * 8 + j;
        hv[j] = (f16)(w[(co * CI + ci) * 9 + tap] * prm[ci * 2]);
    }
    ((f16x8*)wsg)[fr * 64 + lane] = hv;
}

// ------ Pass C/D: 3x3 conv; staging = packed ReLU(t+q); MFMA with scaled weights ------
template <int CI>
__global__ __launch_bounds__(512, 4) void k_conv3(const f16* __restrict__ in,
                                                  const float* __restrict__ wsg,
                                                  const float* __restrict__ prm,
                                                  f16* __restrict__ outp,
                                                  float* __restrict__ bkt) {
    constexpr int KS = CI / 32;
    __shared__ __align__(16) struct {
        f16   Wl[18 * 512];      // 18 KB: current ks weight frags
        f16   Al[6 * 128 * 32];  // 48 KB: staged A tile (rows y0-1..y0+4)
        float red[8][64];
    } sh;
    int tid = threadIdx.x;
    int lane = tid & 63, w = tid >> 6;
    int p = lane & 15, g = lane >> 4;
    int rw = w >> 1, h = w & 1;
    int cw = tid & 3, pxt = tid >> 2;

    unsigned o = blockIdx.x;
    unsigned xcd = o & 7u, q = o >> 3;
    unsigned rg = q & 31u, grp = q >> 5;
    unsigned b = (grp << 3) | xcd;        // batch pinned to XCD for L2 locality
    int y0 = (int)rg * 4;

    // per-channel q = sh/sc (sc>0 since gamma=1): ReLU(sc*t+sh) = sc*ReLU(t+q)
    f16x8 qv[KS];
#pragma unroll
    for (int ks = 0; ks < KS; ++ks)
#pragma unroll
        for (int j = 0; j < 8; ++j) {
            int ch = ks * 32 + cw * 8 + j;
            qv[ks][j] = (f16)(prm[ch * 2 + 1] / prm[ch * 2]);
        }

    bool mask0 = (h == 0 && p == 0);
    bool mask1 = (h == 1 && p == 15);
    const f16x8 kZ = {0, 0, 0, 0, 0, 0, 0, 0};

    f32x4 acc[4][2];
#pragma unroll
    for (int f = 0; f < 4; ++f)
#pragma unroll
        for (int cf = 0; cf < 2; ++cf) acc[f][cf] = (f32x4){0.f, 0.f, 0.f, 0.f};

    for (int ks = 0; ks < KS; ++ks) {
        if (ks) __syncthreads();          // WAR on LDS reuse
        // ---- stage weights (18 KB linear, async) ----
#pragma unroll
        for (int c0 = 0; c0 < 1152; c0 += 512) {
            if (c0 + (w << 6) < 1152) {   // wave-uniform guard
                int c = c0 + tid;
                gl_lds16(wsg + (size_t)(ks * 4608 + c * 4), &sh.Wl[c * 8]);
            }
        }
        // ---- stage A rows: packed fp16 ReLU(t+q); zero at image border ----
#pragma unroll
        for (int r6 = 0; r6 < 6; ++r6) {
            int yy = y0 - 1 + r6;
            f16* dst = &sh.Al[r6 * 4096 + tid * 8];
            if ((unsigned)yy < 128u) {
                const f16* s = in + ((size_t)(b * 128u + (unsigned)yy) * 128u + pxt) * CI
                                  + ks * 32 + cw * 8;
                f16x8 raw = *(const f16x8*)s;
                *(f16x8*)dst = __builtin_elementwise_max(raw + qv[ks], kZ);
            } else {
                *(f16x8*)dst = kZ;
            }
        }
        __syncthreads();
        // ---- 9 taps x 4 px-frags x 2 co-halves ----
        const f16x8* Wv = (const f16x8*)sh.Wl;
        for (int dyi = 0; dyi < 3; ++dyi) {
            int ar = rw + dyi;
#pragma unroll
            for (int dxi = 0; dxi < 3; ++dxi) {
                int tap = dyi * 3 + dxi;
                f16x8 b0 = Wv[(tap * 2 + 0) * 64 + lane];
                f16x8 b1 = Wv[(tap * 2 + 1) * 64 + lane];
#pragma unroll
                for (int f = 0; f < 4; ++f) {
                    int px = h * 64 + f * 16 + p + dxi - 1;
                    f16x8 a = *(const f16x8*)&sh.Al[(ar * 128 + px) * 32 + g * 8];
                    if (dxi == 0 && f == 0) { if (mask0) a = kZ; }
                    if (dxi == 2 && f == 3) { if (mask1) a = kZ; }
                    acc[f][0] = __builtin_amdgcn_mfma_f32_16x16x32_f16(b0, a, acc[f][0], 0, 0, 0);
                    acc[f][1] = __builtin_amdgcn_mfma_f32_16x16x32_f16(b1, a, acc[f][1], 0, 0, 0);
                }
            }
        }
    }

    // ---- stats: lane(p,g) reg r of half cf holds co = cf*16+g*4+r ----
    float sv[8], qvv[8];
#pragma unroll
    for (int cf = 0; cf < 2; ++cf)
#pragma unroll
        for (int r = 0; r < 4; ++r) {
            float s = acc[0][cf][r] + acc[1][cf][r] + acc[2][cf][r] + acc[3][cf][r];
            float qq = acc[0][cf][r] * acc[0][cf][r] + acc[1][cf][r] * acc[1][cf][r] +
                       acc[2][cf][r] * acc[2][cf][r] + acc[3][cf][r] * acc[3][cf][r];
#pragma unroll
            for (int m = 1; m < 16; m <<= 1) {
                s += __shfl_xor(s, m, 64);
                qq += __shfl_xor(qq, m, 64);
            }
            sv[cf * 4 + r] = s; qvv[cf * 4 + r] = qq;
        }
    if (p == 0) {
#pragma unroll
        for (int cf = 0; cf < 2; ++cf)
#pragma unroll
            for (int r = 0; r < 4; ++r) {
                int co = cf * 16 + g * 4 + r;
                sh.red[w][co * 2] = sv[cf * 4 + r];
                sh.red[w][co * 2 + 1] = qvv[cf * 4 + r];
            }
    }

    // ---- store raw fp16 NHWC: lane packs 4 consecutive co -> 8B stores ----
    unsigned pxb = b * 16384u + (unsigned)((y0 + rw) * 128 + h * 64 + p);
#pragma unroll
    for (int f = 0; f < 4; ++f)
#pragma unroll
        for (int cf = 0; cf < 2; ++cf) {
            f16x4 o4 = { (f16)acc[f][cf][0], (f16)acc[f][cf][1],
                         (f16)acc[f][cf][2], (f16)acc[f][cf][3] };
            *(f16x4*)(outp + (size_t)(pxb + f * 16u) * 32u + (unsigned)(cf * 16 + g * 4)) = o4;
        }

    __syncthreads();
    if (tid < 64) {
        float v = 0.f;
#pragma unroll
        for (int ww = 0; ww < 8; ++ww) v += sh.red[ww][tid];
        atomicAdd(&bkt[(o & 63u) * 64u + (unsigned)tid], v);
    }
}

// ---- Pass E: fc head; BN4 scale folded into split W1, packed ReLU(t+q4) staging ----
__global__ __launch_bounds__(TPB) void k_fcm(const f16* __restrict__ t4,
                                             const float* __restrict__ prm4,
                                             const float* __restrict__ fw1,
                                             const float* __restrict__ fb1,
                                             const float* __restrict__ fw2,
                                             const float* __restrict__ fb2,
                                             float* __restrict__ y0sum) {
    __shared__ __align__(16) struct {
        f16   V1[256 * 40];    // ReLU(t+q4) tokens [px][32ch] pad->40
        f16   V2[256 * 40];    // h1 (tanh'd fc1) same layout
        float b1s[32], b2s[16];
        float red[4][16];
    } sh;
    int tid = threadIdx.x, lane = tid & 63, w = tid >> 6;
    int p = lane & 15, g = lane >> 4;
    if (tid < 32) sh.b1s[tid] = fb1[tid];
    if (tid < 16) sh.b2s[tid] = fb2[tid];
    // W1 frags hi/lo, columns pre-scaled by sc4[ci]; W2 frags hi/lo unscaled
    f16x8 W1h[2], W1l[2], W2h, W2l;
#pragma unroll
    for (int cb = 0; cb < 2; ++cb) {
        const float* wr = fw1 + (cb * 16 + p) * 32 + g * 8;
#pragma unroll
        for (int j = 0; j < 8; ++j) {
            float v = wr[j] * prm4[(g * 8 + j) * 2];
            f16 hh = (f16)v;
            W1h[cb][j] = hh;
            W1l[cb][j] = (f16)(v - (float)hh);
        }
    }
    {
        const float* wr = fw2 + p * 32 + g * 8;
#pragma unroll
        for (int j = 0; j < 8; ++j) {
            float v = wr[j];
            f16 hh = (f16)v;
            W2h[j] = hh;
            W2l[j] = (f16)(v - (float)hh);
        }
    }
    // q4 = sh4/sc4 per channel, fp16 packed (sc4>0)
    f16x8 q4v[4];
#pragma unroll
    for (int c8 = 0; c8 < 4; ++c8)
#pragma unroll
        for (int j = 0; j < 8; ++j) {
            int c = c8 * 8 + j;
            q4v[c8][j] = (f16)(prm4[c * 2 + 1] / prm4[c * 2]);
        }
    const f16x8 kZ8 = {0, 0, 0, 0, 0, 0, 0, 0};
    __syncthreads();
    // ---- stage tokens: packed ReLU(t+q4) ----
    unsigned pid = blockIdx.x * TPB + tid;
    const f16x8* tv = (const f16x8*)(t4 + (size_t)pid * 32);
    f16* vp = sh.V1 + tid * 40;
#pragma unroll
    for (int c8 = 0; c8 < 4; ++c8) {
        f16x8 raw = tv[c8];
        *(f16x8*)(vp + c8 * 8) = __builtin_elementwise_max(raw + q4v[c8], kZ8);
    }
    __syncthreads();
    // ---- fc1 via split MFMA: wave w owns px [w*64, w*64+64) ----
    float bb1[8];
#pragma unroll
    for (int cb = 0; cb < 2; ++cb)
#pragma unroll
        for (int r = 0; r < 4; ++r) bb1[cb * 4 + r] = sh.b1s[cb * 16 + g * 4 + r];
#pragma unroll
    for (int f = 0; f < 4; ++f) {
        int pxl = w * 64 + f * 16 + p;
        f16x8 bf = *(const f16x8*)&sh.V1[pxl * 40 + g * 8];
#pragma unroll
        for (int cb = 0; cb < 2; ++cb) {
            f32x4 d = {0.f, 0.f, 0.f, 0.f};
            d = __builtin_amdgcn_mfma_f32_16x16x32_f16(W1l[cb], bf, d, 0, 0, 0);
            d = __builtin_amdgcn_mfma_f32_16x16x32_f16(W1h[cb], bf, d, 0, 0, 0);
            f16x4 h4;
#pragma unroll
            for (int r = 0; r < 4; ++r) h4[r] = (f16)tanh_fast(d[r] + bb1[cb * 4 + r]);
            *(f16x4*)&sh.V2[pxl * 40 + cb * 16 + g * 4] = h4;
        }
    }
    __syncthreads();
    // ---- fc2 via split MFMA + tanh + sum over tokens ----
    float bb2[4];
#pragma unroll
    for (int r = 0; r < 4; ++r) bb2[r] = sh.b2s[g * 4 + r];
    float s4[4] = {0.f, 0.f, 0.f, 0.f};
#pragma unroll
    for (int f = 0; f < 4; ++f) {
        int pxl = w * 64 + f * 16 + p;
        f16x8 bf = *(const f16x8*)&sh.V2[pxl * 40 + g * 8];
        f32x4 d = {0.f, 0.f, 0.f, 0.f};
        d = __builtin_amdgcn_mfma_f32_16x16x32_f16(W2l, bf, d, 0, 0, 0);
        d = __builtin_amdgcn_mfma_f32_16x16x32_f16(W2h, bf, d, 0, 0, 0);
#pragma unroll
        for (int r = 0; r < 4; ++r) s4[r] += tanh_fast(d[r] + bb2[r]);
    }
#pragma unroll
    for (int r = 0; r < 4; ++r) {
#pragma unroll
        for (int m = 1; m < 16; m <<= 1) s4[r] += __shfl_xor(s4[r], m, 64);
    }
    if (p == 0) {
#pragma unroll
        for (int r = 0; r < 4; ++r) sh.red[w][g * 4 + r] = s4[r];
    }
    __syncthreads();
    if (tid < 16) {
        float s = sh.red[0][tid] + sh.red[1][tid] + sh.red[2][tid] + sh.red[3][tid];
        atomicAdd(&y0sum[(blockIdx.x >> 6) * 16u + tid], s);
    }
}

// -------- finalize y0 -> wn, stable argsort, vals/order/wi, Cm, idx --------
__global__ void k_final(const float* __restrict__ y0sum, float* __restrict__ out,
                        float* __restrict__ Cm, int* __restrict__ idxb) {
    int b = threadIdx.x; // 64 threads
    float y0[16]; float nrm = 0.f;
#pragma unroll
    for (int i = 0; i < 16; ++i) { y0[i] = y0sum[b * 16 + i] * (1.0f / 16384.0f); nrm += y0[i] * y0[i]; }
    nrm = sqrtf(nrm);
    float wn[16]; int id[16];
#pragma unroll
    for (int i = 0; i < 16; ++i) { wn[i] = fabsf(y0[i]) * nrm; id[i] = i; }
    for (int i = 1; i < 16; ++i) {
        float k = wn[i]; int ii = id[i]; int j = i - 1;
        while (j >= 0 && wn[j] < k) { wn[j + 1] = wn[j]; id[j + 1] = id[j]; --j; }
        wn[j + 1] = k; id[j + 1] = ii;
    }
    for (int i = 0; i < 16; ++i) {
        out[VALS_OFF + b * 16 + i] = wn[i];
        out[ORDER_OFF + b * 16 + i] = (float)id[i];
    }
    for (int g = 0; g < 5; ++g)
        out[WI_OFF + g * 64 + b] = (wn[g * 3] + wn[g * 3 + 1] + wn[g * 3 + 2]) * (1.0f / 3.0f);
    for (int i = 0; i < 16; ++i)
        for (int j = 0; j < 16; ++j) Cm[b * 256 + i * 16 + j] = y0[i] * y0[j];
    for (int s = 0; s < 15; ++s) idxb[b * 15 + s] = id[s];
}

// -------- read x once -> cgh (Cm @ x) and fi (channel gather) --------
__global__ __launch_bounds__(TPB) void k_out(const float* __restrict__ x,
                                             const float* __restrict__ Cm,
                                             const int* __restrict__ idxb,
                                             float* __restrict__ out) {
    __shared__ float cm[256];
    __shared__ int idl[15];
    int tid = threadIdx.x;
    unsigned b = blockIdx.x >> 6;
    unsigned p = ((blockIdx.x & 63u) << 8) + tid;
    cm[tid] = Cm[b * 256u + tid];
    if (tid < 15) idl[tid] = idxb[b * 15u + tid];
    __syncthreads();
    const float* xp = x + (size_t)b * 16 * HWc + p;
    float xv[16];
#pragma unroll
    for (int j = 0; j < 16; ++j) xv[j] = xp[(size_t)j * HWc];
    float* og = out + CGH_OFF + (size_t)b * 16 * HWc + p;
    for (int i = 0; i < 16; ++i) {
        float a = 0.f;
#pragma unroll
        for (int j = 0; j < 16; ++j) a = fmaf(cm[i * 16 + j], xv[j], a);
        og[(size_t)i * HWc] = a;
    }
#pragma unroll
    for (int s = 0; s < 15; ++s) {
        int ch = idl[s];
        float vv = xp[(size_t)ch * HWc];
        int g = s / 3, r = s - 3 * g;
        out[(size_t)((g * 64 + (int)b) * 3 + r) * HWc + p] = vv;
    }
}

extern "C" void kernel_launch(void* const* d_in, const int* in_sizes, int n_in,
                              void* d_out, int out_size, void* d_ws, size_t ws_size,
                              hipStream_t stream) {
    const float* x    = (const float*)d_in[0];
    const float* w1   = (const float*)d_in[1];
    const float* bn1g = (const float*)d_in[2];  const float* bn1b = (const float*)d_in[3];
    const float* w2   = (const float*)d_in[4];
    const float* bn2g = (const float*)d_in[5];  const float* bn2b = (const float*)d_in[6];
    const float* w3   = (const float*)d_in[7];
    const float* bn3g = (const float*)d_in[8];  const float* bn3b = (const float*)d_in[9];
    const float* w4   = (const float*)d_in[10];
    const float* bn4g = (const float*)d_in[11]; const float* bn4b = (const float*)d_in[12];
    const float* fw1  = (const float*)d_in[13]; const float* fb1  = (const float*)d_in[14];
    const float* fw2  = (const float*)d_in[15]; const float* fb2  = (const float*)d_in[16];
    float* out = (float*)d_out;
    float* wsf = (float*)d_ws;

    // ws layout (float offsets):
    //   t2r @ 0           (33,554,432) : conv2 raw fp16 NHWC [px][64]
    //   t3r @ 33,554,432  (16,777,216) : conv3 raw fp16 NHWC [px][32]
    //   t4h @ 50,331,648  (16,777,216) : conv4 raw fp16 NHWC [px][32]
    //   acc @ 67,108,864  : buckets / params / Cm / idx / weight frags
    f16*   t2r = (f16*)wsf;
    f16*   t3r = (f16*)(wsf + 33554432);
    f16*   t4h = (f16*)(wsf + 50331648);
    float* acc = wsf + 67108864;
    float* b1g = acc;                 // 64*272 = 17408
    float* b2g = acc + 17408;         // 64*800 = 51200
    float* b3  = acc + 68608;         // 8192
    float* b4  = acc + 76800;         // 8192
    float* y0s = acc + 84992;         // 1024   (zeroed range ends at 86016)
    float* pr1 = acc + 86016;  float* pr2 = acc + 86080;
    float* pr3 = acc + 86208;  float* pr4 = acc + 86272;
    float* Cm  = acc + 86336;         // 16384
    int*   idxb = (int*)(acc + 102720); // 960
    float* wsg3 = acc + 103680;       // 9216 floats (36 frags)
    float* wsg4 = acc + 112896;       // 4608 floats (18 frags)
    size_t need = (size_t)(67108864 + 117504) * 4;
    if (ws_size < need) return;

    hipMemsetAsync(acc, 0, 86016 * 4, stream);  // zero all stat buckets + y0sum

    k_gramx<<<512, TPB, 0, stream>>>(x, b1g);
    k_sfin1g<<<1, 256, 0, stream>>>(b1g, w1, bn1g, bn1b, pr1);
    k_conv2m<<<4096, TPB, 0, stream>>>(x, w1, w2, pr1, t2r, b2g);
    k_sfin2g<<<1, 256, 0, stream>>>(b2g, w2, bn2g, bn2b, pr2);
    k_wprep<64><<<9, 256, 0, stream>>>(w3, pr2, wsg3);         // needs pr2 (scale fold)
    k_conv3<64><<<2048, 512, 0, stream>>>(t2r, wsg3, pr2, t3r, b3);
    k_sfin<<<1, 32, 0, stream>>>(b3, bn3g, bn3b, pr3, 32);
    k_wprep<32><<<5, 256, 0, stream>>>(w4, pr3, wsg4);         // needs pr3 (scale fold)
    k_conv3<32><<<2048, 512, 0, stream>>>(t3r, wsg4, pr3, t4h, b4);
    k_sfin<<<1, 32, 0, stream>>>(b4, bn4g, bn4b, pr4, 32);
    k_fcm<<<4096, TPB, 0, stream>>>(t4h, pr4, fw1, fb1, fw2, fb2, y0s);
    k_final<<<1, 64, 0, stream>>>(y0s, out, Cm, idxb);
    k_out<<<4096, TPB, 0, stream>>>(x, Cm, idxb, out);
}